// Round 11
// baseline (115.653 us; speedup 1.0000x reference)
//
#include <hip/hip_runtime.h>
#include <math.h>

#define BATCH 32
#define MROWS 120
#define JDIM  64
#define DIM   512
#define NROW  (BATCH * MROWS)   // 3840

#define LOGIT_SCALE 14.285714285714283f

typedef float  f4     __attribute__((ext_vector_type(4)));
typedef float  f32x4  __attribute__((ext_vector_type(4)));
typedef short  bf16x8 __attribute__((ext_vector_type(8)));
typedef unsigned short u16x4 __attribute__((ext_vector_type(4)));

static __device__ __forceinline__ unsigned short f2bf(float f) {
    // round-to-nearest-even fp32 -> bf16 (inputs are finite normals)
    unsigned int u = __float_as_uint(f);
    u += 0x7FFFu + ((u >> 16) & 1u);
    return (unsigned short)(u >> 16);
}

// ---------------------------------------------------------------------------
// K1: skel_bf[b,m,:] = bf16(normalize(sum_j skel[b,m,j,:]))
// one block per (b,m); 256 threads; wave w reads a contiguous 32 KB
// sub-slab sequentially. SINGLE CHANGE vs R10: plain loads (no nontemporal)
// — A/B of the last unattributed R8-bundle variable.
// ---------------------------------------------------------------------------
__global__ __launch_bounds__(256, 4) void k_skel_mean_norm(
    const float* __restrict__ skel_in, unsigned short* __restrict__ skel_bf)
{
    const int row = blockIdx.x;          // b*120 + m
    const int t   = threadIdx.x;         // 0..255
    const int wid = t >> 6, lane = t & 63;

    const f4* __restrict__ base =
        (const f4*)(skel_in + (size_t)row * (JDIM * DIM)) + wid * 2048 + lane;

    f4 acc0 = (f4){0.f, 0.f, 0.f, 0.f};   // d4-slot = lane
    f4 acc1 = (f4){0.f, 0.f, 0.f, 0.f};   // d4-slot = lane + 64
    #pragma unroll 16
    for (int it2 = 0; it2 < 16; ++it2) {
        f4 a = base[it2 * 128];            // even it
        f4 b = base[it2 * 128 + 64];       // odd it
        acc0 += a;
        acc1 += b;
    }

    // cross-wave combine: lds[w][slot]
    __shared__ f4 lds[4][128];
    lds[wid][lane]      = acc0;
    lds[wid][lane + 64] = acc1;
    __syncthreads();

    f4 acc = (f4){0.f, 0.f, 0.f, 0.f};
    float ss = 0.f;
    if (t < 128) {
        acc = lds[0][t] + lds[1][t] + lds[2][t] + lds[3][t];
        ss = acc.x * acc.x + acc.y * acc.y + acc.z * acc.z + acc.w * acc.w;
    }

    #pragma unroll
    for (int o = 32; o > 0; o >>= 1) ss += __shfl_xor(ss, o, 64);
    __shared__ float wsum[2];
    if (t < 128 && lane == 0) wsum[wid] = ss;
    __syncthreads();
    const float inv = 1.0f / sqrtf(wsum[0] + wsum[1]);

    if (t < 128) {
        u16x4 o;
        o.x = f2bf(acc.x * inv);
        o.y = f2bf(acc.y * inv);
        o.z = f2bf(acc.z * inv);
        o.w = f2bf(acc.w * inv);
        *(u16x4*)(skel_bf + (size_t)row * DIM + 4 * t) = o;
    }
}

// ---------------------------------------------------------------------------
// Kt (FROZEN): text_bf[b,m,:] = bf16( LOGIT_SCALE * text / ||text|| )
// ---------------------------------------------------------------------------
__global__ __launch_bounds__(128) void k_text_prep(
    const float* __restrict__ text, unsigned short* __restrict__ text_bf)
{
    const int row = blockIdx.x;          // b*120 + m
    const int t   = threadIdx.x;         // 0..127
    const int wid = t >> 6, lane = t & 63;

    f4 v = ((const f4*)(text + (size_t)row * DIM))[t];
    float ss = v.x * v.x + v.y * v.y + v.z * v.z + v.w * v.w;
    #pragma unroll
    for (int o = 32; o > 0; o >>= 1) ss += __shfl_xor(ss, o, 64);

    __shared__ float red[2];
    if (lane == 0) red[wid] = ss;
    __syncthreads();
    const float sc = LOGIT_SCALE / sqrtf(red[0] + red[1]);

    u16x4 o;
    o.x = f2bf(v.x * sc);
    o.y = f2bf(v.y * sc);
    o.z = f2bf(v.z * sc);
    o.w = f2bf(v.w * sc);
    *(u16x4*)(text_bf + (size_t)row * DIM + 4 * t) = o;
}

// ---------------------------------------------------------------------------
// K2 (FROZEN): 256 single-wave blocks (block = b*8 + w). Wave owns text rows
// 16w..16w+15 x all 128 cols: 8 col-tiles of mfma_f32_16x16x32_bf16.
// In-register row-LSE + diagonal (C/D: col=lane&15, row=(lane>>4)*4+reg).
// ---------------------------------------------------------------------------
__global__ __launch_bounds__(64) void k_logits_mfma(
    const unsigned short* __restrict__ text_bf,
    const unsigned short* __restrict__ skel_bf,
    float* __restrict__ bpart)
{
    const int blk = blockIdx.x;          // b*8 + w
    const int b   = blk >> 3;
    const int w   = blk & 7;
    const int l   = threadIdx.x;         // 0..63
    const int cl  = l & 15;              // A-row / B-col within tile
    const int cg  = l >> 4;              // k-subgroup; C row-group

    const int arow = 16 * w + cl;
    const bool a_ok = (arow < MROWS);
    const unsigned short* __restrict__ ta =
        text_bf + ((size_t)b * MROWS + arow) * DIM;
    const unsigned short* __restrict__ sb =
        skel_bf + (size_t)b * MROWS * DIM;

    const bf16x8 zerov = (bf16x8){0,0,0,0,0,0,0,0};

    f32x4 acc[8];
    #pragma unroll
    for (int i = 0; i < 8; ++i) acc[i] = (f32x4){0.f, 0.f, 0.f, 0.f};

    for (int ks = 0; ks < 16; ++ks) {
        const int k0 = ks * 32 + cg * 8;
        const bf16x8 a = a_ok ? *(const bf16x8*)(ta + k0) : zerov;
        #pragma unroll
        for (int tc = 0; tc < 8; ++tc) {
            const int n = 16 * tc + cl;
            const bf16x8 bb = (n < MROWS)
                ? *(const bf16x8*)(sb + (size_t)n * DIM + k0) : zerov;
            acc[tc] = __builtin_amdgcn_mfma_f32_16x16x32_bf16(a, bb, acc[tc],
                                                              0, 0, 0);
        }
    }

    float csum = 0.f;
    #pragma unroll
    for (int r = 0; r < 4; ++r) {
        const int row = 16 * w + 4 * cg + r;

        float mx = -INFINITY;
        #pragma unroll
        for (int tc = 0; tc < 8; ++tc)
            if (16 * tc + cl < MROWS) mx = fmaxf(mx, acc[tc][r]);
        #pragma unroll
        for (int o = 1; o < 16; o <<= 1) mx = fmaxf(mx, __shfl_xor(mx, o, 16));

        float se = 0.f;
        #pragma unroll
        for (int tc = 0; tc < 8; ++tc)
            if (16 * tc + cl < MROWS) se += expf(acc[tc][r] - mx);
        #pragma unroll
        for (int o = 1; o < 16; o <<= 1) se += __shfl_xor(se, o, 16);

        if (row < MROWS && cl == 4 * cg + r)
            csum += acc[w][r] - (mx + logf(se));
    }

    #pragma unroll
    for (int o = 32; o > 0; o >>= 1) csum += __shfl_xor(csum, o, 64);
    if (l == 0) bpart[blk] = csum;
}

// ---------------------------------------------------------------------------
// K3 (FROZEN): out = -sum(bpart[256]) / NROW
// ---------------------------------------------------------------------------
__global__ __launch_bounds__(64) void k_final(
    const float* __restrict__ bpart, float* __restrict__ out)
{
    const int t = threadIdx.x;
    float s = 0.f;
    #pragma unroll
    for (int k = 0; k < 4; ++k) s += bpart[t + 64 * k];
    #pragma unroll
    for (int o = 32; o > 0; o >>= 1) s += __shfl_xor(s, o, 64);
    if (t == 0) out[0] = -s * (1.0f / (float)NROW);
}

extern "C" void kernel_launch(void* const* d_in, const int* in_sizes, int n_in,
                              void* d_out, int out_size, void* d_ws, size_t ws_size,
                              hipStream_t stream)
{
    const float* skel_in = (const float*)d_in[0];   // (32,120,64,512) f32
    const float* text    = (const float*)d_in[1];   // (32,120,512)    f32
    float* out = (float*)d_out;

    unsigned short* skel_bf = (unsigned short*)d_ws;            // 3.93 MB
    unsigned short* text_bf = skel_bf + (size_t)NROW * DIM;     // 3.93 MB
    float*          bpart   = (float*)(text_bf + (size_t)NROW * DIM); // 256

    k_skel_mean_norm<<<NROW,      256, 0, stream>>>(skel_in, skel_bf);
    k_text_prep     <<<NROW,      128, 0, stream>>>(text, text_bf);
    k_logits_mfma   <<<BATCH * 8,  64, 0, stream>>>(text_bf, skel_bf, bpart);
    k_final         <<<1,          64, 0, stream>>>(bpart, out);
}

// Round 12
// 105.827 us; speedup vs baseline: 1.0929x; 1.0929x over previous
//
#include <hip/hip_runtime.h>
#include <math.h>

#define BATCH 32
#define MROWS 120
#define JDIM  64
#define DIM   512
#define NROW  (BATCH * MROWS)   // 3840

#define LOGIT_SCALE 14.285714285714283f

typedef float  f4     __attribute__((ext_vector_type(4)));
typedef float  f32x4  __attribute__((ext_vector_type(4)));
typedef short  bf16x8 __attribute__((ext_vector_type(8)));
typedef unsigned short u16x4 __attribute__((ext_vector_type(4)));

static __device__ __forceinline__ unsigned short f2bf(float f) {
    // round-to-nearest-even fp32 -> bf16 (inputs are finite normals)
    unsigned int u = __float_as_uint(f);
    u += 0x7FFFu + ((u >> 16) & 1u);
    return (unsigned short)(u >> 16);
}

// ---------------------------------------------------------------------------
// K1 (fused): per (b,m) row:
//   skel_bf[row,:] = bf16(normalize(sum_j skel[row,j,:]))   [NT stream]
//   text_bf[row,:] = bf16(LOGIT_SCALE * text[row,:]/||text[row,:]||)
// 256 threads; wave w reads a contiguous 32 KB skel sub-slab sequentially
// with nontemporal loads (R10's proven config). Text row (2 KB) loads into
// registers up front (t<128), processed in the epilogue.
// ---------------------------------------------------------------------------
__global__ __launch_bounds__(256, 4) void k_skel_text(
    const float* __restrict__ skel_in, const float* __restrict__ text,
    unsigned short* __restrict__ skel_bf, unsigned short* __restrict__ text_bf)
{
    const int row = blockIdx.x;          // b*120 + m
    const int t   = threadIdx.x;         // 0..255
    const int wid = t >> 6, lane = t & 63;

    // issue text load early; sits in 4 VGPRs during the main loop
    f4 tv = (f4){0.f, 0.f, 0.f, 0.f};
    if (t < 128) tv = ((const f4*)(text + (size_t)row * DIM))[t];

    const f4* __restrict__ base =
        (const f4*)(skel_in + (size_t)row * (JDIM * DIM)) + wid * 2048 + lane;

    f4 acc0 = (f4){0.f, 0.f, 0.f, 0.f};   // d4-slot = lane
    f4 acc1 = (f4){0.f, 0.f, 0.f, 0.f};   // d4-slot = lane + 64
    #pragma unroll 16
    for (int it2 = 0; it2 < 16; ++it2) {
        f4 a = __builtin_nontemporal_load(&base[it2 * 128]);
        f4 b = __builtin_nontemporal_load(&base[it2 * 128 + 64]);
        acc0 += a;
        acc1 += b;
    }

    // cross-wave combine: lds[w][slot]
    __shared__ f4 lds[4][128];
    lds[wid][lane]      = acc0;
    lds[wid][lane + 64] = acc1;
    __syncthreads();

    f4 acc = (f4){0.f, 0.f, 0.f, 0.f};
    float ss = 0.f;
    if (t < 128) {
        acc = lds[0][t] + lds[1][t] + lds[2][t] + lds[3][t];
        ss = acc.x * acc.x + acc.y * acc.y + acc.z * acc.z + acc.w * acc.w;
    }

    #pragma unroll
    for (int o = 32; o > 0; o >>= 1) ss += __shfl_xor(ss, o, 64);
    __shared__ float wsum[2];
    if (t < 128 && lane == 0) wsum[wid] = ss;
    __syncthreads();
    const float inv = 1.0f / sqrtf(wsum[0] + wsum[1]);

    if (t < 128) {
        u16x4 o;
        o.x = f2bf(acc.x * inv);
        o.y = f2bf(acc.y * inv);
        o.z = f2bf(acc.z * inv);
        o.w = f2bf(acc.w * inv);
        *(u16x4*)(skel_bf + (size_t)row * DIM + 4 * t) = o;
    }

    // ---- fused text normalize (waves 0-1 hold the row) ----
    float sst = tv.x * tv.x + tv.y * tv.y + tv.z * tv.z + tv.w * tv.w;
    #pragma unroll
    for (int o = 32; o > 0; o >>= 1) sst += __shfl_xor(sst, o, 64);
    __shared__ float tsum[2];
    if (t < 128 && lane == 0) tsum[wid] = sst;
    __syncthreads();

    if (t < 128) {
        const float sc = LOGIT_SCALE / sqrtf(tsum[0] + tsum[1]);
        u16x4 o;
        o.x = f2bf(tv.x * sc);
        o.y = f2bf(tv.y * sc);
        o.z = f2bf(tv.z * sc);
        o.w = f2bf(tv.w * sc);
        *(u16x4*)(text_bf + (size_t)row * DIM + 4 * t) = o;
    }
}

// ---------------------------------------------------------------------------
// K2 (FROZEN): 256 single-wave blocks (block = b*8 + w). Wave owns text rows
// 16w..16w+15 x all 128 cols: 8 col-tiles of mfma_f32_16x16x32_bf16.
// In-register row-LSE + diagonal (C/D: col=lane&15, row=(lane>>4)*4+reg).
// ---------------------------------------------------------------------------
__global__ __launch_bounds__(64) void k_logits_mfma(
    const unsigned short* __restrict__ text_bf,
    const unsigned short* __restrict__ skel_bf,
    float* __restrict__ bpart)
{
    const int blk = blockIdx.x;          // b*8 + w
    const int b   = blk >> 3;
    const int w   = blk & 7;
    const int l   = threadIdx.x;         // 0..63
    const int cl  = l & 15;              // A-row / B-col within tile
    const int cg  = l >> 4;              // k-subgroup; C row-group

    const int arow = 16 * w + cl;
    const bool a_ok = (arow < MROWS);
    const unsigned short* __restrict__ ta =
        text_bf + ((size_t)b * MROWS + arow) * DIM;
    const unsigned short* __restrict__ sb =
        skel_bf + (size_t)b * MROWS * DIM;

    const bf16x8 zerov = (bf16x8){0,0,0,0,0,0,0,0};

    f32x4 acc[8];
    #pragma unroll
    for (int i = 0; i < 8; ++i) acc[i] = (f32x4){0.f, 0.f, 0.f, 0.f};

    for (int ks = 0; ks < 16; ++ks) {
        const int k0 = ks * 32 + cg * 8;
        const bf16x8 a = a_ok ? *(const bf16x8*)(ta + k0) : zerov;
        #pragma unroll
        for (int tc = 0; tc < 8; ++tc) {
            const int n = 16 * tc + cl;
            const bf16x8 bb = (n < MROWS)
                ? *(const bf16x8*)(sb + (size_t)n * DIM + k0) : zerov;
            acc[tc] = __builtin_amdgcn_mfma_f32_16x16x32_bf16(a, bb, acc[tc],
                                                              0, 0, 0);
        }
    }

    float csum = 0.f;
    #pragma unroll
    for (int r = 0; r < 4; ++r) {
        const int row = 16 * w + 4 * cg + r;

        float mx = -INFINITY;
        #pragma unroll
        for (int tc = 0; tc < 8; ++tc)
            if (16 * tc + cl < MROWS) mx = fmaxf(mx, acc[tc][r]);
        #pragma unroll
        for (int o = 1; o < 16; o <<= 1) mx = fmaxf(mx, __shfl_xor(mx, o, 16));

        float se = 0.f;
        #pragma unroll
        for (int tc = 0; tc < 8; ++tc)
            if (16 * tc + cl < MROWS) se += expf(acc[tc][r] - mx);
        #pragma unroll
        for (int o = 1; o < 16; o <<= 1) se += __shfl_xor(se, o, 16);

        if (row < MROWS && cl == 4 * cg + r)
            csum += acc[w][r] - (mx + logf(se));
    }

    #pragma unroll
    for (int o = 32; o > 0; o >>= 1) csum += __shfl_xor(csum, o, 64);
    if (l == 0) bpart[blk] = csum;
}

// ---------------------------------------------------------------------------
// K3 (FROZEN): out = -sum(bpart[256]) / NROW
// ---------------------------------------------------------------------------
__global__ __launch_bounds__(64) void k_final(
    const float* __restrict__ bpart, float* __restrict__ out)
{
    const int t = threadIdx.x;
    float s = 0.f;
    #pragma unroll
    for (int k = 0; k < 4; ++k) s += bpart[t + 64 * k];
    #pragma unroll
    for (int o = 32; o > 0; o >>= 1) s += __shfl_xor(s, o, 64);
    if (t == 0) out[0] = -s * (1.0f / (float)NROW);
}

extern "C" void kernel_launch(void* const* d_in, const int* in_sizes, int n_in,
                              void* d_out, int out_size, void* d_ws, size_t ws_size,
                              hipStream_t stream)
{
    const float* skel_in = (const float*)d_in[0];   // (32,120,64,512) f32
    const float* text    = (const float*)d_in[1];   // (32,120,512)    f32
    float* out = (float*)d_out;

    unsigned short* skel_bf = (unsigned short*)d_ws;            // 3.93 MB
    unsigned short* text_bf = skel_bf + (size_t)NROW * DIM;     // 3.93 MB
    float*          bpart   = (float*)(text_bf + (size_t)NROW * DIM); // 256

    k_skel_text  <<<NROW,      256, 0, stream>>>(skel_in, text, skel_bf, text_bf);
    k_logits_mfma<<<BATCH * 8,  64, 0, stream>>>(text_bf, skel_bf, bpart);
    k_final      <<<1,          64, 0, stream>>>(bpart, out);
}